// Round 8
// baseline (957.418 us; speedup 1.0000x reference)
//
#include <hip/hip_runtime.h>
#include <math.h>

#define B_ 16
#define S_ 2048
#define H_ 12
#define D_ 64
#define HID 768
#define A_ 40
#define SCALE_ 0.125f
#define CH1 8          // stage1 s-chunks per (b,h)
#define SUBT 64        // s per subtile
#define NSUB 4         // subtiles per block (256 s per block)
#define S2T 128        // stage2 s-tile per block
#define GJ  2088       // G bias table j-extent (j = a-s+2047 in [0,2087])

typedef __attribute__((ext_vector_type(8))) short short8v;   // 8 bf16 (4 VGPR)
typedef __attribute__((ext_vector_type(4))) float f32x4;     // MFMA C/D

__device__ __forceinline__ unsigned f2bf_bits(float x) {
    unsigned u = __float_as_uint(x);
    return (u + 0x7FFFu + ((u >> 16) & 1u)) >> 16;   // RTNE
}

// split 8 fp32 -> hi/lo bf16 via native __bf16 casts (RTNE; compiler emits cvt_pk)
__device__ __forceinline__ void split8c(const float* x, int4& hi, int4& lo) {
    unsigned h[8], l[8];
#pragma unroll
    for (int i = 0; i < 8; i++) {
        __bf16 bh = (__bf16)x[i];
        float hf = (float)bh;
        __bf16 bl = (__bf16)(x[i] - hf);
        h[i] = (unsigned)__builtin_bit_cast(unsigned short, bh);
        l[i] = (unsigned)__builtin_bit_cast(unsigned short, bl);
    }
    hi = make_int4((int)(h[0] | (h[1] << 16)), (int)(h[2] | (h[3] << 16)),
                   (int)(h[4] | (h[5] << 16)), (int)(h[6] | (h[7] << 16)));
    lo = make_int4((int)(l[0] | (l[1] << 16)), (int)(l[2] | (l[3] << 16)),
                   (int)(l[4] | (l[5] << 16)), (int)(l[6] | (l[7] << 16)));
}

// ---------------- W transpose + bf16 hi/lo split: Wt[z][n][k] ----------------
__global__ void wt_convert(const float* __restrict__ Wq, const float* __restrict__ Wk,
                           const float* __restrict__ Wv,
                           unsigned short* __restrict__ Wth, unsigned short* __restrict__ Wtl)
{
    int idx = blockIdx.x * 256 + threadIdx.x;          // 3 * 192 * 768
    if (idx >= 3 * 192 * 768) return;
    int n  = idx % 768;
    int kc = (idx / 768) % 192;
    int z  = idx / (768 * 192);
    const float* W = (z == 0) ? Wq : (z == 1) ? Wk : Wv;
    unsigned short h4[4], l4[4];
#pragma unroll
    for (int i = 0; i < 4; i++) {
        float x = W[(size_t)(4 * kc + i) * HID + n];
        unsigned hb = f2bf_bits(x);
        float hf = __uint_as_float(hb << 16);
        h4[i] = (unsigned short)hb;
        l4[i] = (unsigned short)f2bf_bits(x - hf);
    }
    size_t o = ((size_t)z * HID + n) * HID + 4 * kc;
    *(ushort4*)&Wth[o] = make_ushort4(h4[0], h4[1], h4[2], h4[3]);
    *(ushort4*)&Wtl[o] = make_ushort4(l4[0], l4[1], l4[2], l4[3]);
}

// ---------------- QKV: bf16x3 MFMA GEMM, 128x256 tile, XCD-swizzled flat grid ----------
// Flat 2304 blocks. xcd = L%8 owns 32 consecutive mt groups; the 9 blocks (3nt x 3zz)
// sharing an X-panel are consecutive slots on ONE xcd -> panel stays in that L2.
__global__ __launch_bounds__(512, 2) void qkv_z(
    const float* __restrict__ X,
    const unsigned short* __restrict__ Wth, const unsigned short* __restrict__ Wtl,
    const float* __restrict__ bq, const float* __restrict__ bk, const float* __restrict__ bv,
    float* __restrict__ Q, float* __restrict__ K, float* __restrict__ V)
{
    const int L  = blockIdx.x;
    const int k8 = L & 7, s_ = L >> 3;        // 288 slots per xcd
    const int mt = k8 * 32 + s_ / 9;
    const int sub = s_ % 9;
    const int nt = sub % 3, zz = sub / 3;
    const int m0 = mt * 128, n0 = nt * 256;

    const float* __restrict__ bias = (zz == 0) ? bq : (zz == 1) ? bk : bv;
    float* __restrict__ Out        = (zz == 0) ? Q  : (zz == 1) ? K  : V;
    const unsigned short* __restrict__ Bhg = Wth + (size_t)zz * HID * HID;
    const unsigned short* __restrict__ Blg = Wtl + (size_t)zz * HID * HID;

    __shared__ unsigned short Ah[128][40];   // pad-40 rows (80B): near-conflict-free
    __shared__ unsigned short Al[128][40];
    __shared__ unsigned short Bh[256][40];
    __shared__ unsigned short Bl[256][40];

    const int t = threadIdx.x;
    const int lane = t & 63, w = t >> 6;
    const int wm = (w & 1) * 64, wn = (w >> 1) * 64;   // 2 m-waves x 4 n-waves
    const int fr = lane & 15, kc = lane >> 4;

    const int sr = t >> 2, sca = (t & 3) * 8;    // A staging: 128 rows x 4 chunks of 8
    const int sb = t >> 1, scb = (t & 1) * 16;   // B staging: 256 rows x 2 chunks of 16

    f32x4 acc[4][4];
#pragma unroll
    for (int i = 0; i < 4; i++)
#pragma unroll
        for (int j = 0; j < 4; j++) acc[i][j] = (f32x4){0.f, 0.f, 0.f, 0.f};

    for (int k0 = 0; k0 < HID; k0 += 32) {
        float xv[8];
        const float* xp = X + (size_t)(m0 + sr) * HID + k0 + sca;
        float4 f0 = *(const float4*)xp;
        float4 f1 = *(const float4*)(xp + 4);
        xv[0] = f0.x; xv[1] = f0.y; xv[2] = f0.z; xv[3] = f0.w;
        xv[4] = f1.x; xv[5] = f1.y; xv[6] = f1.z; xv[7] = f1.w;
        int4 ah, al;
        split8c(xv, ah, al);
        size_t bo = (size_t)(n0 + sb) * HID + k0 + scb;
        int4 bh0 = *(const int4*)&Bhg[bo];
        int4 bh1 = *(const int4*)&Bhg[bo + 8];
        int4 bl0 = *(const int4*)&Blg[bo];
        int4 bl1 = *(const int4*)&Blg[bo + 8];

        __syncthreads();   // prior tile's LDS reads complete
        *(int4*)&Ah[sr][sca] = ah;
        *(int4*)&Al[sr][sca] = al;
        *(int4*)&Bh[sb][scb]     = bh0;  *(int4*)&Bh[sb][scb + 8] = bh1;
        *(int4*)&Bl[sb][scb]     = bl0;  *(int4*)&Bl[sb][scb + 8] = bl1;
        __syncthreads();

        short8v a_h[4], a_l[4], b_h[4], b_l[4];
#pragma unroll
        for (int i = 0; i < 4; i++) {
            a_h[i] = *(const short8v*)&Ah[wm + i * 16 + fr][kc * 8];
            a_l[i] = *(const short8v*)&Al[wm + i * 16 + fr][kc * 8];
            b_h[i] = *(const short8v*)&Bh[wn + i * 16 + fr][kc * 8];
            b_l[i] = *(const short8v*)&Bl[wn + i * 16 + fr][kc * 8];
        }
#pragma unroll
        for (int i = 0; i < 4; i++)
#pragma unroll
            for (int j = 0; j < 4; j++) {
                acc[i][j] = __builtin_amdgcn_mfma_f32_16x16x32_bf16(a_h[i], b_h[j], acc[i][j], 0, 0, 0);
                acc[i][j] = __builtin_amdgcn_mfma_f32_16x16x32_bf16(a_l[i], b_h[j], acc[i][j], 0, 0, 0);
                acc[i][j] = __builtin_amdgcn_mfma_f32_16x16x32_bf16(a_h[i], b_l[j], acc[i][j], 0, 0, 0);
            }
    }

    const float scl = (zz == 1) ? SCALE_ : 1.0f;
#pragma unroll
    for (int j = 0; j < 4; j++) {
        int n = n0 + wn + j * 16 + fr;
        float bj = bias[n];
        int h = n >> 6, d = n & 63;
#pragma unroll
        for (int i = 0; i < 4; i++) {
            int mb = m0 + wm + i * 16 + kc * 4;
#pragma unroll
            for (int r = 0; r < 4; r++) {
                int m = mb + r;
                int b = m >> 11, s = m & 2047;
                Out[(((size_t)b * H_ + h) * S_ + s) * D_ + d] = (acc[i][j][r] + bj) * scl;
            }
        }
    }
}

// ---------------- agent pooling ----------------
__global__ void agent_pool(const float* __restrict__ Q, float* __restrict__ Ag)
{
    int idx = blockIdx.x * 256 + threadIdx.x;
    if (idx >= B_ * H_ * A_ * D_) return;
    int d  = idx & 63;
    int a  = (idx >> 6) % A_;
    int bh = idx / (A_ * D_);
    float src = ((float)a + 0.5f) * (2048.0f / 40.0f) - 0.5f;
    src = fminf(fmaxf(src, 0.0f), 2047.0f);
    int lo = (int)floorf(src);
    int hi = min(lo + 1, S_ - 1);
    float w = src - (float)lo;
    const float* base = Q + (size_t)bh * (S_ * D_);
    Ag[idx] = base[lo * D_ + d] * (1.0f - w) + base[hi * D_ + d] * w;
}

// ---------------- G bias precompute: G[bh][a][j] = ag[a] . dist[j] ----------------
__global__ __launch_bounds__(256) void g_bias(
    const float* __restrict__ Ag, const float* __restrict__ dist, float* __restrict__ G)
{
    const int bh = blockIdx.x;     // 192
    const int yc = blockIdx.y;     // 8 chunks of 261 j  (8*261 = 2088)
    const int j0 = yc * 261;
    __shared__ float ag[A_][D_];
    const int t = threadIdx.x;
    for (int i = t; i < A_ * D_ / 4; i += 256)
        ((float4*)ag)[i] = ((const float4*)(Ag + (size_t)bh * (A_ * D_)))[i];
    __syncthreads();
    const int g = t >> 2, dq = t & 3;
    for (int i = g; i < A_ * 261; i += 64) {
        int a = i / 261, jj = i - a * 261;
        int j = j0 + jj;
        const float* dr = dist + (size_t)j * D_ + dq * 16;
        const float* ar = &ag[a][dq * 16];
        float sum = 0.f;
#pragma unroll
        for (int c = 0; c < 4; c++) {
            float4 d4 = *(const float4*)(dr + 4 * c);
            float4 a4 = *(const float4*)(ar + 4 * c);
            sum = fmaf(a4.x, d4.x, sum);
            sum = fmaf(a4.y, d4.y, sum);
            sum = fmaf(a4.z, d4.z, sum);
            sum = fmaf(a4.w, d4.w, sum);
        }
        sum += __shfl_xor(sum, 1);
        sum += __shfl_xor(sum, 2);
        if (dq == 0) G[((size_t)bh * A_ + a) * GJ + j] = sum;
    }
}

// ---------------- stage 1 partial (G path): no pe staging, 4 blocks/CU ----------------
__global__ __launch_bounds__(256, 4) void stage1_part_g(
    const float* __restrict__ Kl, const float* __restrict__ Vl,
    const float* __restrict__ Ag, const float* __restrict__ G,
    const float* __restrict__ mask,
    float* __restrict__ Pacc, float* __restrict__ Pm, float* __restrict__ Pl)
{
    const int q  = blockIdx.x;
    const int bh = blockIdx.y;
    const int b  = bh / H_;
    const int s0 = q * (NSUB * SUBT);
    const float* __restrict__ kb = Kl + (size_t)bh * (S_ * D_);
    const float* __restrict__ vb = Vl + (size_t)bh * (S_ * D_);
    const float* __restrict__ Gb = G + (size_t)bh * A_ * GJ;

    __shared__ float ag[A_][D_];          // 10.0 KB
    __shared__ float pv[SUBT * 68];       // V tile, 17.0 KB
    __shared__ float sc[SUBT][41];        // 10.2 KB
    __shared__ float pm6[6][A_];
    __shared__ float mrow[A_], lrow[A_], resc[A_];

    const int t  = threadIdx.x;
    const int sl = t >> 2, dq = t & 3;

    for (int i = t; i < A_ * D_ / 4; i += 256)
        ((float4*)ag)[i] = ((const float4*)(Ag + (size_t)bh * (A_ * D_)))[i];
    if (t < A_) { mrow[t] = -INFINITY; lrow[t] = 0.0f; }

    float4 acc[3];
#pragma unroll
    for (int ii = 0; ii < 3; ii++) acc[ii] = make_float4(0.f, 0.f, 0.f, 0.f);

    for (int st = 0; st < NSUB; st++) {
        const int sb = s0 + st * SUBT;

        __syncthreads();                  // prior subtile's phase C done reading pv
        // ---- stage V tile ----
        for (int i = t; i < SUBT * 16; i += 256) {
            int r = i >> 4, c = i & 15;
            *(float4*)&pv[r * 68 + c * 4] = *(const float4*)&vb[(size_t)(sb + r) * D_ + c * 4];
        }
        // per-thread K slice: 16 floats of row s = sb + sl
        const int s = sb + sl;
        float4 kreg[4];
        const float* kp = kb + (size_t)s * D_ + dq * 16;
#pragma unroll
        for (int c = 0; c < 4; c++) kreg[c] = *(const float4*)(kp + 4 * c);
        float mval = mask[(size_t)b * S_ + s];

        // ---- scores: QK via regs + G gather (bias precomputed) ----
        for (int a = 0; a < A_; a++) {
            const float* agr = &ag[a][dq * 16];
            float sum = 0.0f;
#pragma unroll
            for (int c = 0; c < 4; c++) {
                float4 a4 = *(const float4*)(agr + 4 * c);
                float4 k4 = kreg[c];
                sum = fmaf(a4.x, k4.x, sum);
                sum = fmaf(a4.y, k4.y, sum);
                sum = fmaf(a4.z, k4.z, sum);
                sum = fmaf(a4.w, k4.w, sum);
            }
            sum += __shfl_xor(sum, 1);
            sum += __shfl_xor(sum, 2);
            if (dq == 0) sc[sl][a] = sum + Gb[(size_t)a * GJ + (a - s + 2047)] + mval;
        }
        __syncthreads();

        // ---- online softmax (split reductions) ----
        if (t < 240) {
            int a = t % 40, r6 = t / 40;
            float mx = -INFINITY;
            for (int i = r6; i < SUBT; i += 6) mx = fmaxf(mx, sc[i][a]);
            pm6[r6][a] = mx;
        }
        __syncthreads();
        if (t < A_) {
            float lm = pm6[0][t];
#pragma unroll
            for (int r6 = 1; r6 < 6; r6++) lm = fmaxf(lm, pm6[r6][t]);
            float mnew = fmaxf(mrow[t], lm);
            resc[t] = __expf(mrow[t] - mnew);
            mrow[t] = mnew;
        }
        __syncthreads();
        for (int i = t; i < SUBT * A_; i += 256) {
            int rr = i / 40, aa = i - rr * 40;
            sc[rr][aa] = __expf(sc[rr][aa] - mrow[aa]);
        }
        __syncthreads();
        if (t < 240) {
            int a = t % 40, r6 = t / 40;
            float sm = 0.0f;
            for (int i = r6; i < SUBT; i += 6) sm += sc[i][a];
            pm6[r6][a] = sm;
        }
        __syncthreads();
        if (t < A_) {
            float ls = pm6[0][t] + pm6[1][t] + pm6[2][t] + pm6[3][t] + pm6[4][t] + pm6[5][t];
            lrow[t] = lrow[t] * resc[t] + ls;
        }

        // ---- phase C: acc[a,d4] = acc*resc[a] + sum_s p * V ----
#pragma unroll
        for (int ii = 0; ii < 3; ii++) {
            int i = t + ii * 256;
            if (i < A_ * 16) {
                int a = i >> 4, d4 = i & 15;
                float rs = resc[a];
                float4 c4 = acc[ii];
                c4.x *= rs; c4.y *= rs; c4.z *= rs; c4.w *= rs;
                for (int rr = 0; rr < SUBT; rr++) {
                    float p = sc[rr][a];
                    float4 v4 = *(const float4*)&pv[rr * 68 + d4 * 4];
                    c4.x = fmaf(p, v4.x, c4.x);
                    c4.y = fmaf(p, v4.y, c4.y);
                    c4.z = fmaf(p, v4.z, c4.z);
                    c4.w = fmaf(p, v4.w, c4.w);
                }
                acc[ii] = c4;
            }
        }
    }
    __syncthreads();
#pragma unroll
    for (int ii = 0; ii < 3; ii++) {
        int i = t + ii * 256;
        if (i < A_ * 16) {
            int a = i >> 4, d4 = i & 15;
            *(float4*)&Pacc[(((size_t)(bh * CH1 + q) * A_) + a) * D_ + d4 * 4] = acc[ii];
        }
    }
    if (t < A_) {
        Pm[(size_t)(bh * CH1 + q) * A_ + t] = mrow[t];
        Pl[(size_t)(bh * CH1 + q) * A_ + t] = lrow[t];
    }
}

// ---------------- stage 1 partial (fallback, round-6 proven): pe-band in LDS ----------
__global__ __launch_bounds__(256, 3) void stage1_part(
    const float* __restrict__ Kl, const float* __restrict__ Vl,
    const float* __restrict__ Ag, const float* __restrict__ dist,
    const float* __restrict__ mask,
    float* __restrict__ Pacc, float* __restrict__ Pm, float* __restrict__ Pl)
{
    const int q  = blockIdx.x;
    const int bh = blockIdx.y;
    const int b  = bh / H_;
    const int s0 = q * (NSUB * SUBT);
    const float* __restrict__ kb = Kl + (size_t)bh * (S_ * D_);
    const float* __restrict__ vb = Vl + (size_t)bh * (S_ * D_);

    __shared__ float ag[A_][D_];
    __shared__ float pv[103 * 68];
    __shared__ float sc[SUBT][44];
    __shared__ float pm6[6][A_];
    __shared__ float mrow[A_], lrow[A_], resc[A_];

    const int t  = threadIdx.x;
    const int sl = t >> 2, dq = t & 3;

    for (int i = t; i < A_ * D_ / 4; i += 256)
        ((float4*)ag)[i] = ((const float4*)(Ag + (size_t)bh * (A_ * D_)))[i];
    if (t < A_) { mrow[t] = -INFINITY; lrow[t] = 0.0f; }

    float4 acc[3];
#pragma unroll
    for (int ii = 0; ii < 3; ii++) acc[ii] = make_float4(0.f, 0.f, 0.f, 0.f);

    for (int st = 0; st < NSUB; st++) {
        const int sb = s0 + st * SUBT;
        const int jbase = 1984 - sb;

        __syncthreads();
        for (int i = t; i < 103 * 16; i += 256) {
            int r = i >> 4, c = i & 15;
            *(float4*)&pv[r * 68 + c * 4] = *(const float4*)&dist[(size_t)(jbase + r) * D_ + c * 4];
        }
        const int s = sb + sl;
        float4 kreg[4];
        const float* kp = kb + (size_t)s * D_ + dq * 16;
#pragma unroll
        for (int c = 0; c < 4; c++) kreg[c] = *(const float4*)(kp + 4 * c);
        float mval = mask[(size_t)b * S_ + s];
        __syncthreads();

        for (int a = 0; a < A_; a++) {
            const float* per = &pv[(a + 63 - sl) * 68 + dq * 16];
            const float* agr = &ag[a][dq * 16];
            float sum = 0.0f;
#pragma unroll
            for (int c = 0; c < 4; c++) {
                float4 p4 = *(const float4*)(per + 4 * c);
                float4 a4 = *(const float4*)(agr + 4 * c);
                float4 k4 = kreg[c];
                sum = fmaf(a4.x, k4.x + p4.x, sum);
                sum = fmaf(a4.y, k4.y + p4.y, sum);
                sum = fmaf(a4.z, k4.z + p4.z, sum);
                sum = fmaf(a4.w, k4.w + p4.w, sum);
            }
            sum += __shfl_xor(sum, 1);
            sum += __shfl_xor(sum, 2);
            if (dq == 0) sc[sl][a] = sum + mval;
        }
        __syncthreads();

        for (int i = t; i < SUBT * 16; i += 256) {
            int r = i >> 4, c = i & 15;
            *(float4*)&pv[r * 68 + c * 4] = *(const float4*)&vb[(size_t)(sb + r) * D_ + c * 4];
        }
        if (t < 240) {
            int a = t % 40, r6 = t / 40;
            float mx = -INFINITY;
            for (int i = r6; i < SUBT; i += 6) mx = fmaxf(mx, sc[i][a]);
            pm6[r6][a] = mx;
        }
        __syncthreads();
        if (t < A_) {
            float lm = pm6[0][t];
#pragma unroll
            for (int r6 = 1; r6 < 6; r6++) lm = fmaxf(lm, pm6[r6][t]);
            float mnew = fmaxf(mrow[t], lm);
            resc[t] = __expf(mrow[t] - mnew);
            mrow[t] = mnew;
        }
        __syncthreads();
        for (int i = t; i < SUBT * A_; i += 256) {
            int rr = i / 40, aa = i - rr * 40;
            sc[rr][aa] = __expf(sc[rr][aa] - mrow[aa]);
        }
        __syncthreads();
        if (t < 240) {
            int a = t % 40, r6 = t / 40;
            float sm = 0.0f;
            for (int i = r6; i < SUBT; i += 6) sm += sc[i][a];
            pm6[r6][a] = sm;
        }
        __syncthreads();
        if (t < A_) {
            float ls = pm6[0][t] + pm6[1][t] + pm6[2][t] + pm6[3][t] + pm6[4][t] + pm6[5][t];
            lrow[t] = lrow[t] * resc[t] + ls;
        }

#pragma unroll
        for (int ii = 0; ii < 3; ii++) {
            int i = t + ii * 256;
            if (i < A_ * 16) {
                int a = i >> 4, d4 = i & 15;
                float rs = resc[a];
                float4 c4 = acc[ii];
                c4.x *= rs; c4.y *= rs; c4.z *= rs; c4.w *= rs;
                for (int rr = 0; rr < SUBT; rr++) {
                    float p = sc[rr][a];
                    float4 v4 = *(const float4*)&pv[rr * 68 + d4 * 4];
                    c4.x = fmaf(p, v4.x, c4.x);
                    c4.y = fmaf(p, v4.y, c4.y);
                    c4.z = fmaf(p, v4.z, c4.z);
                    c4.w = fmaf(p, v4.w, c4.w);
                }
                acc[ii] = c4;
            }
        }
    }
    __syncthreads();
#pragma unroll
    for (int ii = 0; ii < 3; ii++) {
        int i = t + ii * 256;
        if (i < A_ * 16) {
            int a = i >> 4, d4 = i & 15;
            *(float4*)&Pacc[(((size_t)(bh * CH1 + q) * A_) + a) * D_ + d4 * 4] = acc[ii];
        }
    }
    if (t < A_) {
        Pm[(size_t)(bh * CH1 + q) * A_ + t] = mrow[t];
        Pl[(size_t)(bh * CH1 + q) * A_ + t] = lrow[t];
    }
}

// ---------------- stage 1 reduce ----------------
__global__ __launch_bounds__(256) void stage1_reduce(
    const float* __restrict__ Pacc, const float* __restrict__ Pm,
    const float* __restrict__ Pl, float* __restrict__ AgV)
{
    const int bh = blockIdx.x;
    const int t = threadIdx.x;
    __shared__ float F[CH1][A_], Linv[A_];
    if (t < A_) {
        float M = -INFINITY;
#pragma unroll
        for (int q = 0; q < CH1; q++) M = fmaxf(M, Pm[(size_t)(bh * CH1 + q) * A_ + t]);
        float L = 0.0f;
#pragma unroll
        for (int q = 0; q < CH1; q++) {
            float f = __expf(Pm[(size_t)(bh * CH1 + q) * A_ + t] - M);
            F[q][t] = f;
            L = fmaf(f, Pl[(size_t)(bh * CH1 + q) * A_ + t], L);
        }
        Linv[t] = 1.0f / L;
    }
    __syncthreads();
#pragma unroll
    for (int ii = 0; ii < 3; ii++) {
        int i = t + ii * 256;
        if (i < A_ * 16) {
            int a = i >> 4, d4 = i & 15;
            float4 s4 = make_float4(0.f, 0.f, 0.f, 0.f);
            for (int q = 0; q < CH1; q++) {
                float f = F[q][a];
                float4 p4 = *(const float4*)&Pacc[(((size_t)(bh * CH1 + q) * A_) + a) * D_ + d4 * 4];
                s4.x = fmaf(f, p4.x, s4.x);
                s4.y = fmaf(f, p4.y, s4.y);
                s4.z = fmaf(f, p4.z, s4.z);
                s4.w = fmaf(f, p4.w, s4.w);
            }
            float inv = Linv[a];
            s4.x *= inv; s4.y *= inv; s4.z *= inv; s4.w *= inv;
            *(float4*)&AgV[(size_t)bh * (A_ * D_) + a * D_ + d4 * 4] = s4;
        }
    }
}

// ---------------- stage 2: LDS dist-band, 128 s per block, 2 threads/s ----------------
__global__ __launch_bounds__(256, 2) void stage2(
    const float* __restrict__ Ql, const float* __restrict__ Ag,
    const float* __restrict__ AgV, const float* __restrict__ dist,
    float* __restrict__ Out)
{
    const int s0 = blockIdx.x * S2T;
    const int bh = blockIdx.y;
    const int b = bh / H_, h = bh % H_;
    const int t = threadIdx.x;
    const int sl = t >> 1;
    const int hf = t & 1;
    const int s  = s0 + sl;
    const int doff = hf * 32;

    __shared__ float band[167 * 68];
    __shared__ float ag2[A_][68];
    __shared__ float av[A_][68];

    const int jbase = s0 + 2008;
    for (int i = t; i < 167 * 16; i += 256) {
        int r = i >> 4, c = i & 15;
        *(float4*)&band[r * 68 + c * 4] = *(const float4*)&dist[(size_t)(jbase + r) * D_ + c * 4];
    }
    for (int i = t; i < A_ * 16; i += 256) {
        int r = i >> 4, c = i & 15;
        float4 g = *(const float4*)&Ag[(size_t)bh * (A_ * D_) + r * D_ + c * 4];
        g.x *= SCALE_; g.y *= SCALE_; g.z *= SCALE_; g.w *= SCALE_;
        *(float4*)&ag2[r][c * 4] = g;
        *(float4*)&av[r][c * 4] = *(const float4*)&AgV[(size_t)bh * (A_ * D_) + r * D_ + c * 4];
    }

    const float* __restrict__ qrow = Ql + ((size_t)bh * S_ + s) * D_ + doff;
    float4 fq[8];
#pragma unroll
    for (int c = 0; c < 8; c++) fq[c] = *(const float4*)&qrow[c * 4];
    __syncthreads();

    float sc[A_];
#pragma unroll
    for (int a = 0; a < A_; a++) {
        const float* pe = &band[(sl + 39 - a) * 68 + doff];
        const float* ar = &ag2[a][doff];
        float sum = 0.0f;
#pragma unroll
        for (int c = 0; c < 8; c++) {
            float4 p4 = *(const float4*)&pe[c * 4];
            float4 a4 = *(const float4*)&ar[c * 4];
            float4 q4 = fq[c];
            sum = fmaf(q4.x, a4.x + p4.x, sum);
            sum = fmaf(q4.y, a4.y + p4.y, sum);
            sum = fmaf(q4.z, a4.z + p4.z, sum);
            sum = fmaf(q4.w, a4.w + p4.w, sum);
        }
        sum += __shfl_xor(sum, 1);
        sc[a] = sum;
    }

    float mx = -INFINITY;
#pragma unroll
    for (int a = 0; a < A_; a++) mx = fmaxf(mx, sc[a]);
    float sum = 0.0f;
#pragma unroll
    for (int a = 0; a < A_; a++) {
        float p = __expf(sc[a] - mx);
        sc[a] = p;
        sum += p;
    }
    float inv = 1.0f / sum;

    float4 o[8];
#pragma unroll
    for (int c = 0; c < 8; c++) o[c] = make_float4(0.f, 0.f, 0.f, 0.f);
#pragma unroll
    for (int a = 0; a < A_; a++) {
        float p = sc[a] * inv;
        const float* vr = &av[a][doff];
#pragma unroll
        for (int c = 0; c < 8; c++) {
            float4 vv = *(const float4*)&vr[c * 4];
            o[c].x = fmaf(p, vv.x, o[c].x);
            o[c].y = fmaf(p, vv.y, o[c].y);
            o[c].z = fmaf(p, vv.z, o[c].z);
            o[c].w = fmaf(p, vv.w, o[c].w);
        }
    }
    float* orow = Out + ((size_t)b * S_ + s) * HID + h * D_ + doff;
#pragma unroll
    for (int c = 0; c < 8; c++) *(float4*)&orow[c * 4] = o[c];
}

extern "C" void kernel_launch(void* const* d_in, const int* in_sizes, int n_in,
                              void* d_out, int out_size, void* d_ws, size_t ws_size,
                              hipStream_t stream) {
    const float* hs   = (const float*)d_in[0];
    const float* mask = (const float*)d_in[1];
    const float* Wq   = (const float*)d_in[2];
    const float* bq   = (const float*)d_in[3];
    const float* Wk   = (const float*)d_in[4];
    const float* bk   = (const float*)d_in[5];
    const float* Wv   = (const float*)d_in[6];
    const float* bv   = (const float*)d_in[7];
    const float* dist = (const float*)d_in[8];
    float* out = (float*)d_out;

    float* ws = (float*)d_ws;
    const size_t QKV = (size_t)B_ * H_ * S_ * D_;   // 25,165,824 floats each
    const size_t AG  = (size_t)B_ * H_ * A_ * D_;   // 491,520 floats
    float* Q     = ws;
    float* K     = ws + QKV;
    float* V     = ws + 2 * QKV;
    float* Agent = ws + 3 * QKV;
    float* AgV   = Agent + AG;
    float* Pacc  = AgV + AG;
    float* Pm    = Pacc + (size_t)B_ * H_ * CH1 * A_ * D_;
    float* Pl    = Pm + (size_t)B_ * H_ * CH1 * A_;
    unsigned short* Wth = (unsigned short*)(Pl + (size_t)B_ * H_ * CH1 * A_);
    unsigned short* Wtl = Wth + (size_t)3 * HID * HID;
    float* G = (float*)(Wtl + (size_t)3 * HID * HID);
    // base (proven) footprint ends at G; G adds 192*40*2088*4 = 64.1 MB
    const size_t BASE_BYTES = ((size_t)(3 * QKV + 2 * AG)
                             + (size_t)B_ * H_ * CH1 * A_ * D_
                             + 2 * (size_t)B_ * H_ * CH1 * A_) * 4
                             + (size_t)2 * 3 * HID * HID * 2;
    const size_t G_BYTES = (size_t)B_ * H_ * A_ * GJ * 4;
    const bool use_g = (ws_size >= BASE_BYTES + G_BYTES);

    wt_convert<<<(3 * 192 * 768 + 255) / 256, 256, 0, stream>>>(Wq, Wk, Wv, Wth, Wtl);
    qkv_z<<<2304, 512, 0, stream>>>(hs, Wth, Wtl, bq, bk, bv, Q, K, V);
    agent_pool<<<(B_ * H_ * A_ * D_ + 255) / 256, 256, 0, stream>>>(Q, Agent);
    dim3 g1(CH1, B_ * H_);
    if (use_g) {
        dim3 gb(B_ * H_, 8);
        g_bias<<<gb, 256, 0, stream>>>(Agent, dist, G);
        stage1_part_g<<<g1, 256, 0, stream>>>(K, V, Agent, G, mask, Pacc, Pm, Pl);
    } else {
        stage1_part<<<g1, 256, 0, stream>>>(K, V, Agent, dist, mask, Pacc, Pm, Pl);
    }
    stage1_reduce<<<B_ * H_, 256, 0, stream>>>(Pacc, Pm, Pl, AgV);
    dim3 g2(S_ / S2T, B_ * H_);
    stage2<<<g2, 256, 0, stream>>>(Q, Agent, AgV, dist, out);
}

// Round 9
// 696.384 us; speedup vs baseline: 1.3748x; 1.3748x over previous
//
#include <hip/hip_runtime.h>
#include <math.h>

#define B_ 16
#define S_ 2048
#define H_ 12
#define D_ 64
#define HID 768
#define A_ 40
#define SCALE_ 0.125f
#define CH1 8          // stage1 s-chunks per (b,h)
#define SUBT 64        // s per subtile
#define NSUB 4         // subtiles per block (256 s per block)
#define S2T 128        // stage2 s-tile per block

typedef __attribute__((ext_vector_type(8))) short short8v;    // 8 bf16 (4 VGPR)
typedef __attribute__((ext_vector_type(4))) float f32x4;
typedef __attribute__((ext_vector_type(16))) float f32x16;    // 32x32 MFMA C/D

__device__ __forceinline__ unsigned f2bf_bits(float x) {
    unsigned u = __float_as_uint(x);
    return (u + 0x7FFFu + ((u >> 16) & 1u)) >> 16;   // RTNE
}

// split 8 fp32 -> hi/lo bf16 via native __bf16 casts (RTNE)
__device__ __forceinline__ void split8c(const float* x, int4& hi, int4& lo) {
    unsigned h[8], l[8];
#pragma unroll
    for (int i = 0; i < 8; i++) {
        __bf16 bh = (__bf16)x[i];
        float hf = (float)bh;
        __bf16 bl = (__bf16)(x[i] - hf);
        h[i] = (unsigned)__builtin_bit_cast(unsigned short, bh);
        l[i] = (unsigned)__builtin_bit_cast(unsigned short, bl);
    }
    hi = make_int4((int)(h[0] | (h[1] << 16)), (int)(h[2] | (h[3] << 16)),
                   (int)(h[4] | (h[5] << 16)), (int)(h[6] | (h[7] << 16)));
    lo = make_int4((int)(l[0] | (l[1] << 16)), (int)(l[2] | (l[3] << 16)),
                   (int)(l[4] | (l[5] << 16)), (int)(l[6] | (l[7] << 16)));
}

// ---------------- W transpose + bf16 hi/lo split: Wt[z][n][k] ----------------
__global__ void wt_convert(const float* __restrict__ Wq, const float* __restrict__ Wk,
                           const float* __restrict__ Wv,
                           unsigned short* __restrict__ Wth, unsigned short* __restrict__ Wtl)
{
    int idx = blockIdx.x * 256 + threadIdx.x;          // 3 * 192 * 768
    if (idx >= 3 * 192 * 768) return;
    int n  = idx % 768;
    int kc = (idx / 768) % 192;
    int z  = idx / (768 * 192);
    const float* W = (z == 0) ? Wq : (z == 1) ? Wk : Wv;
    unsigned short h4[4], l4[4];
#pragma unroll
    for (int i = 0; i < 4; i++) {
        float x = W[(size_t)(4 * kc + i) * HID + n];
        unsigned hb = f2bf_bits(x);
        float hf = __uint_as_float(hb << 16);
        h4[i] = (unsigned short)hb;
        l4[i] = (unsigned short)f2bf_bits(x - hf);
    }
    size_t o = ((size_t)z * HID + n) * HID + 4 * kc;
    *(ushort4*)&Wth[o] = make_ushort4(h4[0], h4[1], h4[2], h4[3]);
    *(ushort4*)&Wtl[o] = make_ushort4(l4[0], l4[1], l4[2], l4[3]);
}

// ---------------- QKV: bf16x3 MFMA GEMM (32x32x16), 128x256 tile, XCD-swizzled ----------
__global__ __launch_bounds__(512, 2) void qkv_z(
    const float* __restrict__ X,
    const unsigned short* __restrict__ Wth, const unsigned short* __restrict__ Wtl,
    const float* __restrict__ bq, const float* __restrict__ bk, const float* __restrict__ bv,
    float* __restrict__ Q, float* __restrict__ K, float* __restrict__ V)
{
    const int L   = blockIdx.x;
    const int k8  = L & 7, sl_ = L >> 3;      // 288 slots per xcd
    const int mt  = k8 * 32 + sl_ / 9;
    const int sub = sl_ % 9;
    const int nt  = sub % 3, zz = sub / 3;
    const int m0 = mt * 128, n0 = nt * 256;

    const float* __restrict__ bias = (zz == 0) ? bq : (zz == 1) ? bk : bv;
    float* __restrict__ Out        = (zz == 0) ? Q  : (zz == 1) ? K  : V;
    const unsigned short* __restrict__ Bhg = Wth + (size_t)zz * HID * HID;
    const unsigned short* __restrict__ Blg = Wtl + (size_t)zz * HID * HID;

    __shared__ unsigned short Ah[128][40];   // 20-word rows: frag reads conflict-free
    __shared__ unsigned short Al[128][40];
    __shared__ unsigned short Bh[256][40];
    __shared__ unsigned short Bl[256][40];

    const int t = threadIdx.x;
    const int lane = t & 63, w = t >> 6;
    const int wm = (w & 1) * 64, wn = (w >> 1) * 64;   // 2 m-waves x 4 n-waves
    const int r32 = lane & 31, kh = lane >> 5;         // 32x32 frag: row, k-half

    const int sr = t >> 2, sca = (t & 3) * 8;    // A staging: 128 rows x 4 chunks of 8
    const int sb = t >> 1, scb = (t & 1) * 16;   // B staging: 256 rows x 2 chunks of 16

    f32x16 acc[2][2];
#pragma unroll
    for (int i = 0; i < 2; i++)
#pragma unroll
        for (int j = 0; j < 2; j++)
#pragma unroll
            for (int p = 0; p < 16; p++) acc[i][j][p] = 0.f;

    for (int k0 = 0; k0 < HID; k0 += 32) {
        // ---- global -> reg (+convert A) ----
        float xv[8];
        const float* xp = X + (size_t)(m0 + sr) * HID + k0 + sca;
        float4 f0 = *(const float4*)xp;
        float4 f1 = *(const float4*)(xp + 4);
        xv[0] = f0.x; xv[1] = f0.y; xv[2] = f0.z; xv[3] = f0.w;
        xv[4] = f1.x; xv[5] = f1.y; xv[6] = f1.z; xv[7] = f1.w;
        int4 ah, al;
        split8c(xv, ah, al);
        size_t bo = (size_t)(n0 + sb) * HID + k0 + scb;
        int4 bh0 = *(const int4*)&Bhg[bo];
        int4 bh1 = *(const int4*)&Bhg[bo + 8];
        int4 bl0 = *(const int4*)&Blg[bo];
        int4 bl1 = *(const int4*)&Blg[bo + 8];

        __syncthreads();   // prior tile's LDS reads complete
        *(int4*)&Ah[sr][sca] = ah;
        *(int4*)&Al[sr][sca] = al;
        *(int4*)&Bh[sb][scb]     = bh0;  *(int4*)&Bh[sb][scb + 8] = bh1;
        *(int4*)&Bl[sb][scb]     = bl0;  *(int4*)&Bl[sb][scb + 8] = bl1;
        __syncthreads();

        // ---- fragments + MFMA: 2 k-steps of 16 ----
#pragma unroll
        for (int ks = 0; ks < 2; ks++) {
            const int ko = ks * 16 + kh * 8;
            short8v a_h[2], a_l[2], b_h[2], b_l[2];
#pragma unroll
            for (int i = 0; i < 2; i++) {
                a_h[i] = *(const short8v*)&Ah[wm + i * 32 + r32][ko];
                a_l[i] = *(const short8v*)&Al[wm + i * 32 + r32][ko];
                b_h[i] = *(const short8v*)&Bh[wn + i * 32 + r32][ko];
                b_l[i] = *(const short8v*)&Bl[wn + i * 32 + r32][ko];
            }
#pragma unroll
            for (int i = 0; i < 2; i++)
#pragma unroll
                for (int j = 0; j < 2; j++) {
                    acc[i][j] = __builtin_amdgcn_mfma_f32_32x32x16_bf16(a_h[i], b_h[j], acc[i][j], 0, 0, 0);
                    acc[i][j] = __builtin_amdgcn_mfma_f32_32x32x16_bf16(a_l[i], b_h[j], acc[i][j], 0, 0, 0);
                    acc[i][j] = __builtin_amdgcn_mfma_f32_32x32x16_bf16(a_h[i], b_l[j], acc[i][j], 0, 0, 0);
                }
        }
    }

    // ---- epilogue: C/D layout col=lane&31, row=(p&3)+8*(p>>2)+4*(lane>>5) ----
    const float scl = (zz == 1) ? SCALE_ : 1.0f;
#pragma unroll
    for (int j = 0; j < 2; j++) {
        int n = n0 + wn + j * 32 + r32;
        float bj = bias[n];
        int h = n >> 6, d = n & 63;
#pragma unroll
        for (int i = 0; i < 2; i++) {
#pragma unroll
            for (int p = 0; p < 16; p++) {
                int m = m0 + wm + i * 32 + (p & 3) + 8 * (p >> 2) + 4 * kh;
                int b = m >> 11, s = m & 2047;
                Out[(((size_t)b * H_ + h) * S_ + s) * D_ + d] = (acc[i][j][p] + bj) * scl;
            }
        }
    }
}

// ---------------- agent pooling ----------------
__global__ void agent_pool(const float* __restrict__ Q, float* __restrict__ Ag)
{
    int idx = blockIdx.x * 256 + threadIdx.x;
    if (idx >= B_ * H_ * A_ * D_) return;
    int d  = idx & 63;
    int a  = (idx >> 6) % A_;
    int bh = idx / (A_ * D_);
    float src = ((float)a + 0.5f) * (2048.0f / 40.0f) - 0.5f;
    src = fminf(fmaxf(src, 0.0f), 2047.0f);
    int lo = (int)floorf(src);
    int hi = min(lo + 1, S_ - 1);
    float w = src - (float)lo;
    const float* base = Q + (size_t)bh * (S_ * D_);
    Ag[idx] = base[lo * D_ + d] * (1.0f - w) + base[hi * D_ + d] * w;
}

// ---------------- stage 1 partial (round-6 proven): pe-band in LDS ----------------
__global__ __launch_bounds__(256, 3) void stage1_part(
    const float* __restrict__ Kl, const float* __restrict__ Vl,
    const float* __restrict__ Ag, const float* __restrict__ dist,
    const float* __restrict__ mask,
    float* __restrict__ Pacc, float* __restrict__ Pm, float* __restrict__ Pl)
{
    const int q  = blockIdx.x;
    const int bh = blockIdx.y;
    const int b  = bh / H_;
    const int s0 = q * (NSUB * SUBT);
    const float* __restrict__ kb = Kl + (size_t)bh * (S_ * D_);
    const float* __restrict__ vb = Vl + (size_t)bh * (S_ * D_);

    __shared__ float ag[A_][D_];
    __shared__ float pv[103 * 68];
    __shared__ float sc[SUBT][44];
    __shared__ float pm6[6][A_];
    __shared__ float mrow[A_], lrow[A_], resc[A_];

    const int t  = threadIdx.x;
    const int sl = t >> 2, dq = t & 3;

    for (int i = t; i < A_ * D_ / 4; i += 256)
        ((float4*)ag)[i] = ((const float4*)(Ag + (size_t)bh * (A_ * D_)))[i];
    if (t < A_) { mrow[t] = -INFINITY; lrow[t] = 0.0f; }

    float4 acc[3];
#pragma unroll
    for (int ii = 0; ii < 3; ii++) acc[ii] = make_float4(0.f, 0.f, 0.f, 0.f);

    for (int st = 0; st < NSUB; st++) {
        const int sb = s0 + st * SUBT;
        const int jbase = 1984 - sb;

        __syncthreads();
        for (int i = t; i < 103 * 16; i += 256) {
            int r = i >> 4, c = i & 15;
            *(float4*)&pv[r * 68 + c * 4] = *(const float4*)&dist[(size_t)(jbase + r) * D_ + c * 4];
        }
        const int s = sb + sl;
        float4 kreg[4];
        const float* kp = kb + (size_t)s * D_ + dq * 16;
#pragma unroll
        for (int c = 0; c < 4; c++) kreg[c] = *(const float4*)(kp + 4 * c);
        float mval = mask[(size_t)b * S_ + s];
        __syncthreads();

        for (int a = 0; a < A_; a++) {
            const float* per = &pv[(a + 63 - sl) * 68 + dq * 16];
            const float* agr = &ag[a][dq * 16];
            float sum = 0.0f;
#pragma unroll
            for (int c = 0; c < 4; c++) {
                float4 p4 = *(const float4*)(per + 4 * c);
                float4 a4 = *(const float4*)(agr + 4 * c);
                float4 k4 = kreg[c];
                sum = fmaf(a4.x, k4.x + p4.x, sum);
                sum = fmaf(a4.y, k4.y + p4.y, sum);
                sum = fmaf(a4.z, k4.z + p4.z, sum);
                sum = fmaf(a4.w, k4.w + p4.w, sum);
            }
            sum += __shfl_xor(sum, 1);
            sum += __shfl_xor(sum, 2);
            if (dq == 0) sc[sl][a] = sum + mval;
        }
        __syncthreads();

        for (int i = t; i < SUBT * 16; i += 256) {
            int r = i >> 4, c = i & 15;
            *(float4*)&pv[r * 68 + c * 4] = *(const float4*)&vb[(size_t)(sb + r) * D_ + c * 4];
        }
        if (t < 240) {
            int a = t % 40, r6 = t / 40;
            float mx = -INFINITY;
            for (int i = r6; i < SUBT; i += 6) mx = fmaxf(mx, sc[i][a]);
            pm6[r6][a] = mx;
        }
        __syncthreads();
        if (t < A_) {
            float lm = pm6[0][t];
#pragma unroll
            for (int r6 = 1; r6 < 6; r6++) lm = fmaxf(lm, pm6[r6][t]);
            float mnew = fmaxf(mrow[t], lm);
            resc[t] = __expf(mrow[t] - mnew);
            mrow[t] = mnew;
        }
        __syncthreads();
        for (int i = t; i < SUBT * A_; i += 256) {
            int rr = i / 40, aa = i - rr * 40;
            sc[rr][aa] = __expf(sc[rr][aa] - mrow[aa]);
        }
        __syncthreads();
        if (t < 240) {
            int a = t % 40, r6 = t / 40;
            float sm = 0.0f;
            for (int i = r6; i < SUBT; i += 6) sm += sc[i][a];
            pm6[r6][a] = sm;
        }
        __syncthreads();
        if (t < A_) {
            float ls = pm6[0][t] + pm6[1][t] + pm6[2][t] + pm6[3][t] + pm6[4][t] + pm6[5][t];
            lrow[t] = lrow[t] * resc[t] + ls;
        }

#pragma unroll
        for (int ii = 0; ii < 3; ii++) {
            int i = t + ii * 256;
            if (i < A_ * 16) {
                int a = i >> 4, d4 = i & 15;
                float rs = resc[a];
                float4 c4 = acc[ii];
                c4.x *= rs; c4.y *= rs; c4.z *= rs; c4.w *= rs;
                for (int rr = 0; rr < SUBT; rr++) {
                    float p = sc[rr][a];
                    float4 v4 = *(const float4*)&pv[rr * 68 + d4 * 4];
                    c4.x = fmaf(p, v4.x, c4.x);
                    c4.y = fmaf(p, v4.y, c4.y);
                    c4.z = fmaf(p, v4.z, c4.z);
                    c4.w = fmaf(p, v4.w, c4.w);
                }
                acc[ii] = c4;
            }
        }
    }
    __syncthreads();
#pragma unroll
    for (int ii = 0; ii < 3; ii++) {
        int i = t + ii * 256;
        if (i < A_ * 16) {
            int a = i >> 4, d4 = i & 15;
            *(float4*)&Pacc[(((size_t)(bh * CH1 + q) * A_) + a) * D_ + d4 * 4] = acc[ii];
        }
    }
    if (t < A_) {
        Pm[(size_t)(bh * CH1 + q) * A_ + t] = mrow[t];
        Pl[(size_t)(bh * CH1 + q) * A_ + t] = lrow[t];
    }
}

// ---------------- stage 1 reduce ----------------
__global__ __launch_bounds__(256) void stage1_reduce(
    const float* __restrict__ Pacc, const float* __restrict__ Pm,
    const float* __restrict__ Pl, float* __restrict__ AgV)
{
    const int bh = blockIdx.x;
    const int t = threadIdx.x;
    __shared__ float F[CH1][A_], Linv[A_];
    if (t < A_) {
        float M = -INFINITY;
#pragma unroll
        for (int q = 0; q < CH1; q++) M = fmaxf(M, Pm[(size_t)(bh * CH1 + q) * A_ + t]);
        float L = 0.0f;
#pragma unroll
        for (int q = 0; q < CH1; q++) {
            float f = __expf(Pm[(size_t)(bh * CH1 + q) * A_ + t] - M);
            F[q][t] = f;
            L = fmaf(f, Pl[(size_t)(bh * CH1 + q) * A_ + t], L);
        }
        Linv[t] = 1.0f / L;
    }
    __syncthreads();
#pragma unroll
    for (int ii = 0; ii < 3; ii++) {
        int i = t + ii * 256;
        if (i < A_ * 16) {
            int a = i >> 4, d4 = i & 15;
            float4 s4 = make_float4(0.f, 0.f, 0.f, 0.f);
            for (int q = 0; q < CH1; q++) {
                float f = F[q][a];
                float4 p4 = *(const float4*)&Pacc[(((size_t)(bh * CH1 + q) * A_) + a) * D_ + d4 * 4];
                s4.x = fmaf(f, p4.x, s4.x);
                s4.y = fmaf(f, p4.y, s4.y);
                s4.z = fmaf(f, p4.z, s4.z);
                s4.w = fmaf(f, p4.w, s4.w);
            }
            float inv = Linv[a];
            s4.x *= inv; s4.y *= inv; s4.z *= inv; s4.w *= inv;
            *(float4*)&AgV[(size_t)bh * (A_ * D_) + a * D_ + d4 * 4] = s4;
        }
    }
}

// ---------------- stage 2: LDS dist-band, 128 s per block, 2 threads/s ----------------
__global__ __launch_bounds__(256, 2) void stage2(
    const float* __restrict__ Ql, const float* __restrict__ Ag,
    const float* __restrict__ AgV, const float* __restrict__ dist,
    float* __restrict__ Out)
{
    const int s0 = blockIdx.x * S2T;
    const int bh = blockIdx.y;
    const int b = bh / H_, h = bh % H_;
    const int t = threadIdx.x;
    const int sl = t >> 1;
    const int hf = t & 1;
    const int s  = s0 + sl;
    const int doff = hf * 32;

    __shared__ float band[167 * 68];
    __shared__ float ag2[A_][68];
    __shared__ float av[A_][68];

    const int jbase = s0 + 2008;
    for (int i = t; i < 167 * 16; i += 256) {
        int r = i >> 4, c = i & 15;
        *(float4*)&band[r * 68 + c * 4] = *(const float4*)&dist[(size_t)(jbase + r) * D_ + c * 4];
    }
    for (int i = t; i < A_ * 16; i += 256) {
        int r = i >> 4, c = i & 15;
        float4 g = *(const float4*)&Ag[(size_t)bh * (A_ * D_) + r * D_ + c * 4];
        g.x *= SCALE_; g.y *= SCALE_; g.z *= SCALE_; g.w *= SCALE_;
        *(float4*)&ag2[r][c * 4] = g;
        *(float4*)&av[r][c * 4] = *(const float4*)&AgV[(size_t)bh * (A_ * D_) + r * D_ + c * 4];
    }

    const float* __restrict__ qrow = Ql + ((size_t)bh * S_ + s) * D_ + doff;
    float4 fq[8];
#pragma unroll
    for (int c = 0; c < 8; c++) fq[c] = *(const float4*)&qrow[c * 4];
    __syncthreads();

    float sc[A_];
#pragma unroll
    for (int a = 0; a < A_; a++) {
        const float* pe = &band[(sl + 39 - a) * 68 + doff];
        const float* ar = &ag2[a][doff];
        float sum = 0.0f;
#pragma unroll
        for (int c = 0; c < 8; c++) {
            float4 p4 = *(const float4*)&pe[c * 4];
            float4 a4 = *(const float4*)&ar[c * 4];
            float4 q4 = fq[c];
            sum = fmaf(q4.x, a4.x + p4.x, sum);
            sum = fmaf(q4.y, a4.y + p4.y, sum);
            sum = fmaf(q4.z, a4.z + p4.z, sum);
            sum = fmaf(q4.w, a4.w + p4.w, sum);
        }
        sum += __shfl_xor(sum, 1);
        sc[a] = sum;
    }

    float mx = -INFINITY;
#pragma unroll
    for (int a = 0; a < A_; a++) mx = fmaxf(mx, sc[a]);
    float sum = 0.0f;
#pragma unroll
    for (int a = 0; a < A_; a++) {
        float p = __expf(sc[a] - mx);
        sc[a] = p;
        sum += p;
    }
    float inv = 1.0f / sum;

    float4 o[8];
#pragma unroll
    for (int c = 0; c < 8; c++) o[c] = make_float4(0.f, 0.f, 0.f, 0.f);
#pragma unroll
    for (int a = 0; a < A_; a++) {
        float p = sc[a] * inv;
        const float* vr = &av[a][doff];
#pragma unroll
        for (int c = 0; c < 8; c++) {
            float4 vv = *(const float4*)&vr[c * 4];
            o[c].x = fmaf(p, vv.x, o[c].x);
            o[c].y = fmaf(p, vv.y, o[c].y);
            o[c].z = fmaf(p, vv.z, o[c].z);
            o[c].w = fmaf(p, vv.w, o[c].w);
        }
    }
    float* orow = Out + ((size_t)b * S_ + s) * HID + h * D_ + doff;
#pragma unroll
    for (int c = 0; c < 8; c++) *(float4*)&orow[c * 4] = o[c];
}

extern "C" void kernel_launch(void* const* d_in, const int* in_sizes, int n_in,
                              void* d_out, int out_size, void* d_ws, size_t ws_size,
                              hipStream_t stream) {
    const float* hs   = (const float*)d_in[0];
    const float* mask = (const float*)d_in[1];
    const float* Wq   = (const float*)d_in[2];
    const float* bq   = (const float*)d_in[3];
    const float* Wk   = (const float*)d_in[4];
    const float* bk   = (const float*)d_in[5];
    const float* Wv   = (const float*)d_in[6];
    const float* bv   = (const float*)d_in[7];
    const float* dist = (const float*)d_in[8];
    float* out = (float*)d_out;

    float* ws = (float*)d_ws;
    const size_t QKV = (size_t)B_ * H_ * S_ * D_;   // 25,165,824 floats each
    const size_t AG  = (size_t)B_ * H_ * A_ * D_;   // 491,520 floats
    float* Q     = ws;
    float* K     = ws + QKV;
    float* V     = ws + 2 * QKV;
    float* Agent = ws + 3 * QKV;
    float* AgV   = Agent + AG;
    float* Pacc  = AgV + AG;
    float* Pm    = Pacc + (size_t)B_ * H_ * CH1 * A_ * D_;
    float* Pl    = Pm + (size_t)B_ * H_ * CH1 * A_;
    unsigned short* Wth = (unsigned short*)(Pl + (size_t)B_ * H_ * CH1 * A_);
    unsigned short* Wtl = Wth + (size_t)3 * HID * HID;
    // total ws: ~329 MB (proven round-6 layout)

    wt_convert<<<(3 * 192 * 768 + 255) / 256, 256, 0, stream>>>(Wq, Wk, Wv, Wth, Wtl);
    qkv_z<<<2304, 512, 0, stream>>>(hs, Wth, Wtl, bq, bk, bv, Q, K, V);
    agent_pool<<<(B_ * H_ * A_ * D_ + 255) / 256, 256, 0, stream>>>(Q, Agent);
    dim3 g1(CH1, B_ * H_);
    stage1_part<<<g1, 256, 0, stream>>>(K, V, Agent, dist, mask, Pacc, Pm, Pl);
    stage1_reduce<<<B_ * H_, 256, 0, stream>>>(Pacc, Pm, Pl, AgV);
    dim3 g2(S_ / S2T, B_ * H_);
    stage2<<<g2, 256, 0, stream>>>(Q, Agent, AgV, dist, out);
}